// Round 7
// baseline (110.535 us; speedup 1.0000x reference)
//
#include <hip/hip_runtime.h>
#include <math.h>

// Problem constants: B=64, IN=1024, OUT=512, T=512, V_TH=1, TAU=16
#define BATCH   64
#define INS     1024
#define OUTS    512
#define TSTEPS  512
#define TAUF    16.0f

// ---------------------------------------------------------------------------
// Fused pre-kernel: blocks [0,128) tiled weight transpose w[OUT,IN]->wT[IN,OUT];
// blocks [128,192) per-batch spike prep + counting sort by activation time.
//   alpha(t-s) = e^{-t/tau} * (t*A + C) for t > s,
//   A = exp(1 + s/tau)/tau,  C = -s*A,  t_on = floor(s)+1 in [1,256].
// Record per spike (sorted by t_on): {A, int_bits(idx*OUTS/2), C, int_bits(t_on)}
// Also writes bucket starts[b][tau] (tau in [0,257]) = # spikes with t_on < tau,
// so the scan kernel can walk exact time-bucket ranges.
// ---------------------------------------------------------------------------
#define TT 64
#define NTRANS ((INS / TT) * (OUTS / TT))   // 128 transpose blocks

__global__ __launch_bounds__(256) void pre_kernel(
        const float* __restrict__ w, float* __restrict__ wT,
        const float* __restrict__ in_spike, float4* __restrict__ spk,
        int* __restrict__ starts) {
    __shared__ float tile[TT][TT + 1];
    __shared__ int hist[257];
    __shared__ int cursor[257];
    __shared__ int scanbuf[256];

    if (blockIdx.x < NTRANS) {
        const int i0 = (blockIdx.x & (INS / TT - 1)) * TT;
        const int o0 = (blockIdx.x / (INS / TT)) * TT;
        const int c  = threadIdx.x & 63;
        const int r  = threadIdx.x >> 6;
#pragma unroll
        for (int rr = r; rr < TT; rr += 4)
            tile[rr][c] = w[(o0 + rr) * INS + i0 + c];
        __syncthreads();
#pragma unroll
        for (int rr = r; rr < TT; rr += 4)
            wT[(i0 + rr) * OUTS + o0 + c] = tile[c][rr];
        return;
    }

    const int b = blockIdx.x - NTRANS;
    for (int k = threadIdx.x; k < 257; k += 256) hist[k] = 0;
    __syncthreads();

    float sv[INS / 256];
    int   tv[INS / 256];
#pragma unroll
    for (int j = 0; j < INS / 256; ++j) {
        int i = threadIdx.x + j * 256;
        float s = in_spike[b * INS + i];
        sv[j] = s;
        int t = (int)floorf(s) + 1;
        t = t < 1 ? 1 : (t > 256 ? 256 : t);
        tv[j] = t;
        atomicAdd(&hist[t], 1);
    }
    __syncthreads();

    const int tid = threadIdx.x;
    int v = hist[tid + 1];
    scanbuf[tid] = v;
    __syncthreads();
#pragma unroll
    for (int off = 1; off < 256; off <<= 1) {
        int add = (tid >= off) ? scanbuf[tid - off] : 0;
        __syncthreads();
        scanbuf[tid] += add;
        __syncthreads();
    }
    int excl = scanbuf[tid] - v;          // # spikes with t_on < tid+1
    cursor[tid + 1] = excl;
    starts[b * 258 + tid + 1] = excl;
    if (tid == 0) { starts[b * 258] = 0; starts[b * 258 + 257] = INS; }
    __syncthreads();

#pragma unroll
    for (int j = 0; j < INS / 256; ++j) {
        int i = threadIdx.x + j * 256;
        int t = tv[j];
        int pos = atomicAdd(&cursor[t], 1);
        float A = expf(fmaf(sv[j], 1.0f / TAUF, 1.0f)) * (1.0f / TAUF);
        float C = -sv[j] * A;
        spk[b * INS + pos] =
            make_float4(A, __int_as_float(i * (OUTS / 2)), C, __int_as_float(t));
    }
}

// ---------------------------------------------------------------------------
// Scan kernel, time-aligned windows.  Block = (b, 64 outputs), 1024 threads:
// threadIdx.x = lane (32) owning outputs (2x, 2x+1) via float2 gathers;
// threadIdx.y = g (32) owning the FIXED time window [8g+1, 8g+8] and exactly
// the spikes with t_on in that window (bucket range from starts[]).
// Pass 1: window sums (spikes from global, 32-lane broadcast reads).
// LDS float4 prefix scan over g -> exclusive prefix + totals.
// Pass 2: re-walk own window's spikes interleaved with the 8 checks; tail
// [257,512) split 8 steps per g using totals.  Windows partition the time
// axis -> atomicMin over per-window first crossings is exact.
//   V(t) >= 1  <=>  fma(t, SA, SC) >= exp(t/tau)   (sE in LDS).
// Grid = 64*8 = 512 blocks; __launch_bounds__(1024,8) -> exactly 2 blocks/CU
// = 32 waves/CU (VGPR cap 64; all loops rolled, no arrays -> no spill).
// Wave = 32 lanes x 2 g-rows: spike reads broadcast, sE 2-way (free, m136).
// ---------------------------------------------------------------------------
#define OL 32            // lanes per block (each owns 2 outputs)
#define G  32            // time windows
#define WS 8             // steps per window (G*WS = 256 covers all t_on)
#define TAIL0 257        // first spike-free time step

__global__ __launch_bounds__(OL * G, 8) void spike_scan_kernel(
        const float4* __restrict__ spk, const int* __restrict__ starts,
        const float* __restrict__ wT, float* __restrict__ out) {
    const int b = blockIdx.x;
    const int x = threadIdx.x;           // 0..31 lane
    const int g = threadIdx.y;           // 0..31 window
    const int tid = g * OL + x;

    __shared__ float4 ps[G][OL];         // (pA0,pC0,pA1,pC1) 16 KB
    __shared__ float  sE[TSTEPS];        // 2 KB
    __shared__ int    sFirst[2 * OL];    // 256 B

    if (tid < TSTEPS) sE[tid] = expf((float)tid * (1.0f / TAUF));
    if (tid < 2 * OL) sFirst[tid] = TSTEPS;

    const float4* __restrict__ bspk = spk + b * INS;
    const int* __restrict__ sb = starts + b * 258;
    const int w0 = g * WS + 1;           // first time step of window
    const int kBeg = sb[w0];
    const int kEnd = sb[w0 + WS];
    const float2* __restrict__ wT2x = (const float2*)wT + (blockIdx.y * OL + x);

    // ---- pass 1: window sums for outputs (2x, 2x+1) ----
    float pA0 = 0.f, pC0 = 0.f, pA1 = 0.f, pC1 = 0.f;
    for (int k = kBeg; k < kEnd; ++k) {
        float4 p = bspk[k];
        float2 w = wT2x[__float_as_int(p.y)];
        pA0 = fmaf(w.x, p.x, pA0); pC0 = fmaf(w.x, p.z, pC0);
        pA1 = fmaf(w.y, p.x, pA1); pC1 = fmaf(w.y, p.z, pC1);
    }
    ps[g][x] = make_float4(pA0, pC0, pA1, pC1);
    __syncthreads();

    // ---- exclusive prefix over g + full totals ----
    float SA0 = 0.f, SC0 = 0.f, SA1 = 0.f, SC1 = 0.f;
    float TA0 = 0.f, TC0 = 0.f, TA1 = 0.f, TC1 = 0.f;
    for (int j = 0; j < G; ++j) {
        float4 q = ps[j][x];
        if (j == g) { SA0 = TA0; SC0 = TC0; SA1 = TA1; SC1 = TC1; }
        TA0 += q.x; TC0 += q.y; TA1 += q.z; TC1 += q.w;
    }

    int tcur = w0;
    const int tend = w0 + WS;
    int f0 = TSTEPS, f1 = TSTEPS;

#define ADVANCE_TO(TK)                                                        \
    while (tcur < (TK)) {                                                     \
        float e = sE[tcur]; float tf = (float)tcur;                           \
        if (f0 == TSTEPS && fmaf(tf, SA0, SC0) >= e) f0 = tcur;               \
        if (f1 == TSTEPS && fmaf(tf, SA1, SC1) >= e) f1 = tcur;               \
        if (f0 != TSTEPS && f1 != TSTEPS) goto pass2_done;                    \
        ++tcur;                                                               \
    }

    // ---- pass 2: re-walk window spikes with interleaved checks ----
    for (int k = kBeg; k < kEnd; ++k) {
        float4 p = bspk[k];
        int tk = __float_as_int(p.w);
        ADVANCE_TO(tk);
        float2 w = wT2x[__float_as_int(p.y)];
        SA0 = fmaf(w.x, p.x, SA0); SC0 = fmaf(w.x, p.z, SC0);
        SA1 = fmaf(w.y, p.x, SA1); SC1 = fmaf(w.y, p.z, SC1);
    }
    ADVANCE_TO(tend);
#undef ADVANCE_TO

pass2_done:
    // ---- distributed spike-free tail [TAIL0, TSTEPS): 8 steps per g ----
    {
        int ts = TAIL0 + g * WS;
        int te = ts + WS > TSTEPS ? TSTEPS : ts + WS;
        bool need0 = (f0 == TSTEPS);
        bool need1 = (f1 == TSTEPS);
        if (need0 | need1) {
            for (int t = ts; t < te; ++t) {
                float e = sE[t]; float tf = (float)t;
                if (need0 && fmaf(tf, TA0, TC0) >= e) { f0 = t; need0 = false; }
                if (need1 && fmaf(tf, TA1, TC1) >= e) { f1 = t; need1 = false; }
            }
        }
    }

    if (f0 < TSTEPS) atomicMin(&sFirst[2 * x], f0);
    if (f1 < TSTEPS) atomicMin(&sFirst[2 * x + 1], f1);
    __syncthreads();
    if (tid < 2 * OL)
        out[b * OUTS + blockIdx.y * (2 * OL) + tid] = (float)sFirst[tid];
}

// ---------------------------------------------------------------------------
extern "C" void kernel_launch(void* const* d_in, const int* in_sizes, int n_in,
                              void* d_out, int out_size, void* d_ws, size_t ws_size,
                              hipStream_t stream) {
    const float* in_spike = (const float*)d_in[0];   // [B, IN] fp32
    const float* weight   = (const float*)d_in[1];   // [OUT, IN] fp32
    float* out = (float*)d_out;                      // [B, OUT] fp32

    // ws layout: wT 2 MB | spk 1 MB | starts 64*258 ints (~66 KB)
    float*  wT     = (float*)d_ws;
    float4* spk    = (float4*)((char*)d_ws + (size_t)INS * OUTS * sizeof(float));
    int*    starts = (int*)((char*)d_ws + (size_t)INS * OUTS * sizeof(float)
                                        + (size_t)BATCH * INS * sizeof(float4));

    pre_kernel<<<NTRANS + BATCH, 256, 0, stream>>>(weight, wT, in_spike, spk, starts);
    spike_scan_kernel<<<dim3(BATCH, OUTS / (2 * OL)), dim3(OL, G), 0, stream>>>(
        spk, starts, wT, out);
}

// Round 8
// 88.620 us; speedup vs baseline: 1.2473x; 1.2473x over previous
//
#include <hip/hip_runtime.h>
#include <math.h>

// Problem constants: B=64, IN=1024, OUT=512, T=512, V_TH=1, TAU=16
#define BATCH   64
#define INS     1024
#define OUTS    512
#define TSTEPS  512
#define TAUF    16.0f
// log2(e)/TAU for exp(t/tau) == exp2(t * LOG2E_OVER_TAU)
#define LOG2E_OVER_TAU 0.0901684400555602f

// ---------------------------------------------------------------------------
// Fused pre-kernel: blocks [0,128) tiled weight transpose w[OUT,IN]->wT[IN,OUT];
// blocks [128,192) per-batch spike prep + counting sort by activation time.
//   alpha(t-s) = e^{-t/tau} * (t*A + C) for t > s,
//   A = exp(1 + s/tau)/tau,  C = -s*A,  t_on = floor(s)+1 in [1,256].
// Record per spike (sorted by t_on): {A, int_bits(idx*OUTS/2), C, int_bits(t_on)}
// Also writes starts[b][tau], tau in [0,257]: # spikes with t_on < tau.
// ---------------------------------------------------------------------------
#define TT 64
#define NTRANS ((INS / TT) * (OUTS / TT))   // 128 transpose blocks

__global__ __launch_bounds__(256) void pre_kernel(
        const float* __restrict__ w, float* __restrict__ wT,
        const float* __restrict__ in_spike, float4* __restrict__ spk,
        int* __restrict__ starts) {
    __shared__ float tile[TT][TT + 1];
    __shared__ int hist[257];
    __shared__ int cursor[257];
    __shared__ int scanbuf[256];

    if (blockIdx.x < NTRANS) {
        const int i0 = (blockIdx.x & (INS / TT - 1)) * TT;
        const int o0 = (blockIdx.x / (INS / TT)) * TT;
        const int c  = threadIdx.x & 63;
        const int r  = threadIdx.x >> 6;
#pragma unroll
        for (int rr = r; rr < TT; rr += 4)
            tile[rr][c] = w[(o0 + rr) * INS + i0 + c];
        __syncthreads();
#pragma unroll
        for (int rr = r; rr < TT; rr += 4)
            wT[(i0 + rr) * OUTS + o0 + c] = tile[c][rr];
        return;
    }

    const int b = blockIdx.x - NTRANS;
    for (int k = threadIdx.x; k < 257; k += 256) hist[k] = 0;
    __syncthreads();

    float sv[INS / 256];
    int   tv[INS / 256];
#pragma unroll
    for (int j = 0; j < INS / 256; ++j) {
        int i = threadIdx.x + j * 256;
        float s = in_spike[b * INS + i];
        sv[j] = s;
        int t = (int)floorf(s) + 1;
        t = t < 1 ? 1 : (t > 256 ? 256 : t);
        tv[j] = t;
        atomicAdd(&hist[t], 1);
    }
    __syncthreads();

    const int tid = threadIdx.x;
    int v = hist[tid + 1];
    scanbuf[tid] = v;
    __syncthreads();
#pragma unroll
    for (int off = 1; off < 256; off <<= 1) {
        int add = (tid >= off) ? scanbuf[tid - off] : 0;
        __syncthreads();
        scanbuf[tid] += add;
        __syncthreads();
    }
    int excl = scanbuf[tid] - v;          // # spikes with t_on < tid+1
    cursor[tid + 1] = excl;
    starts[b * 258 + tid + 1] = excl;
    if (tid == 0) { starts[b * 258] = 0; starts[b * 258 + 257] = INS; }
    __syncthreads();

#pragma unroll
    for (int j = 0; j < INS / 256; ++j) {
        int i = threadIdx.x + j * 256;
        int t = tv[j];
        int pos = atomicAdd(&cursor[t], 1);
        float A = expf(fmaf(sv[j], 1.0f / TAUF, 1.0f)) * (1.0f / TAUF);
        float C = -sv[j] * A;
        spk[b * INS + pos] =
            make_float4(A, __int_as_float(i * (OUTS / 2)), C, __int_as_float(t));
    }
}

// ---------------------------------------------------------------------------
// Scan kernel: time-aligned windows + LDS staging + branchless mask checks.
// Block = (b, 64 outputs), 1024 threads: threadIdx.x = lane (32) owning
// outputs (2x,2x+1) via float2 gathers; threadIdx.y = g (32) owning the time
// window [8g+1, 8g+8] and exactly the spikes with t_on in it (bucket ranges
// from starts[], wave-uniform).  Spikes staged to LDS (1 float4/thread).
// Pass 1 (4-wide unrolled): window sums.  LDS float2-plane prefix scan over
// g -> exclusive prefix + totals.  Pass 2: walk sub-ranges [sSt[t], sSt[t+1])
// between consecutive checks (no per-spike compares); crossing bits collected
// in a mask -> first = w0 + ffs(mask) - 1.  No early exits, no
// data-dependent branches.  Spike-free tail [257,512) split 8 steps per g
// using totals.  Windows+tail partition the time axis -> atomicMin exact.
//   V(t) >= 1  <=>  fma(t, SA, SC) >= exp2(t*log2e/tau)  (1 mul + v_exp).
// Grid = 64*8 = 512 blocks -> exactly 2 blocks/CU = 32 waves/CU.
// ---------------------------------------------------------------------------
#define OL 32            // lanes per block (each owns 2 outputs)
#define G  32            // time windows
#define WS 8             // steps per window (G*WS = 256 covers all t_on)
#define TAIL0 257        // first spike-free time step

__global__ __launch_bounds__(OL * G, 8) void spike_scan_kernel(
        const float4* __restrict__ spk, const int* __restrict__ starts,
        const float* __restrict__ wT, float* __restrict__ out) {
    const int b = blockIdx.x;
    const int x = threadIdx.x;           // 0..31 lane
    const int g = threadIdx.y;           // 0..31 window
    const int tid = g * OL + x;

    __shared__ float4 sspk[INS];         // 16 KB
    __shared__ float2 psP0[G][OL];       // 8 KB (A0,C0)
    __shared__ float2 psP1[G][OL];       // 8 KB (A1,C1)
    __shared__ int    sSt[258];          // 1 KB
    __shared__ int    sFirst[2 * OL];    // 256 B

    sspk[tid] = spk[b * INS + tid];
    if (tid < 258) sSt[tid] = starts[b * 258 + tid];
    if (tid < 2 * OL) sFirst[tid] = TSTEPS;
    __syncthreads();

    const int w0 = g * WS + 1;           // first time step of window
    const int kBeg = sSt[w0];
    const int kEnd = sSt[w0 + WS];
    const float2* __restrict__ wT2x = (const float2*)wT + (blockIdx.y * OL + x);

    // ---- pass 1: window sums, 4-wide unrolled (wave-uniform bounds) ----
    float pA0 = 0.f, pC0 = 0.f, pA1 = 0.f, pC1 = 0.f;
    int k = kBeg;
    for (; k + 4 <= kEnd; k += 4) {
        float4 p0 = sspk[k + 0];
        float4 p1 = sspk[k + 1];
        float4 p2 = sspk[k + 2];
        float4 p3 = sspk[k + 3];
        float2 q0 = wT2x[__float_as_int(p0.y)];
        float2 q1 = wT2x[__float_as_int(p1.y)];
        float2 q2 = wT2x[__float_as_int(p2.y)];
        float2 q3 = wT2x[__float_as_int(p3.y)];
        pA0 = fmaf(q0.x, p0.x, pA0); pC0 = fmaf(q0.x, p0.z, pC0);
        pA1 = fmaf(q0.y, p0.x, pA1); pC1 = fmaf(q0.y, p0.z, pC1);
        pA0 = fmaf(q1.x, p1.x, pA0); pC0 = fmaf(q1.x, p1.z, pC0);
        pA1 = fmaf(q1.y, p1.x, pA1); pC1 = fmaf(q1.y, p1.z, pC1);
        pA0 = fmaf(q2.x, p2.x, pA0); pC0 = fmaf(q2.x, p2.z, pC0);
        pA1 = fmaf(q2.y, p2.x, pA1); pC1 = fmaf(q2.y, p2.z, pC1);
        pA0 = fmaf(q3.x, p3.x, pA0); pC0 = fmaf(q3.x, p3.z, pC0);
        pA1 = fmaf(q3.y, p3.x, pA1); pC1 = fmaf(q3.y, p3.z, pC1);
    }
    for (; k < kEnd; ++k) {
        float4 p = sspk[k];
        float2 q = wT2x[__float_as_int(p.y)];
        pA0 = fmaf(q.x, p.x, pA0); pC0 = fmaf(q.x, p.z, pC0);
        pA1 = fmaf(q.y, p.x, pA1); pC1 = fmaf(q.y, p.z, pC1);
    }
    psP0[g][x] = make_float2(pA0, pC0);
    psP1[g][x] = make_float2(pA1, pC1);
    __syncthreads();

    // ---- exclusive prefix over g + full totals ----
    float SA0 = 0.f, SC0 = 0.f, SA1 = 0.f, SC1 = 0.f;
    float TA0 = 0.f, TC0 = 0.f, TA1 = 0.f, TC1 = 0.f;
    for (int j = 0; j < G; ++j) {
        float2 q0 = psP0[j][x];
        float2 q1 = psP1[j][x];
        if (j == g) { SA0 = TA0; SC0 = TC0; SA1 = TA1; SC1 = TC1; }
        TA0 += q0.x; TC0 += q0.y; TA1 += q1.x; TC1 += q1.y;
    }

    // ---- pass 2: boundary-driven walk + branchless mask checks ----
    unsigned m0 = 0, m1 = 0;
    float tf = (float)w0;
    k = kBeg;
    for (int d = 0; d < WS; ++d) {
        int e = sSt[w0 + d + 1];         // spikes with t_on <= w0+d
        while (k < e) {
            float4 p = sspk[k];
            float2 q = wT2x[__float_as_int(p.y)];
            SA0 = fmaf(q.x, p.x, SA0); SC0 = fmaf(q.x, p.z, SC0);
            SA1 = fmaf(q.y, p.x, SA1); SC1 = fmaf(q.y, p.z, SC1);
            ++k;
        }
        float ev = exp2f(tf * LOG2E_OVER_TAU);
        m0 |= (fmaf(tf, SA0, SC0) >= ev) ? (1u << d) : 0u;
        m1 |= (fmaf(tf, SA1, SC1) >= ev) ? (1u << d) : 0u;
        tf += 1.0f;
    }
    int f0 = m0 ? (w0 + __builtin_ffs(m0) - 1) : TSTEPS;
    int f1 = m1 ? (w0 + __builtin_ffs(m1) - 1) : TSTEPS;

    // ---- distributed spike-free tail [TAIL0, TSTEPS): 8 steps per g ----
    {
        const int t0 = TAIL0 + g * WS;
        unsigned n0 = 0, n1 = 0;
        float tg = (float)t0;
        for (int d = 0; d < WS; ++d) {
            if (t0 + d < TSTEPS) {
                float ev = exp2f(tg * LOG2E_OVER_TAU);
                n0 |= (fmaf(tg, TA0, TC0) >= ev) ? (1u << d) : 0u;
                n1 |= (fmaf(tg, TA1, TC1) >= ev) ? (1u << d) : 0u;
            }
            tg += 1.0f;
        }
        if (n0) f0 = min(f0, t0 + __builtin_ffs(n0) - 1);
        if (n1) f1 = min(f1, t0 + __builtin_ffs(n1) - 1);
    }

    if (f0 < TSTEPS) atomicMin(&sFirst[2 * x], f0);
    if (f1 < TSTEPS) atomicMin(&sFirst[2 * x + 1], f1);
    __syncthreads();
    if (tid < 2 * OL)
        out[b * OUTS + blockIdx.y * (2 * OL) + tid] = (float)sFirst[tid];
}

// ---------------------------------------------------------------------------
extern "C" void kernel_launch(void* const* d_in, const int* in_sizes, int n_in,
                              void* d_out, int out_size, void* d_ws, size_t ws_size,
                              hipStream_t stream) {
    const float* in_spike = (const float*)d_in[0];   // [B, IN] fp32
    const float* weight   = (const float*)d_in[1];   // [OUT, IN] fp32
    float* out = (float*)d_out;                      // [B, OUT] fp32

    // ws layout: wT 2 MB | spk 1 MB | starts 64*258 ints (~66 KB)
    float*  wT     = (float*)d_ws;
    float4* spk    = (float4*)((char*)d_ws + (size_t)INS * OUTS * sizeof(float));
    int*    starts = (int*)((char*)d_ws + (size_t)INS * OUTS * sizeof(float)
                                        + (size_t)BATCH * INS * sizeof(float4));

    pre_kernel<<<NTRANS + BATCH, 256, 0, stream>>>(weight, wT, in_spike, spk, starts);
    spike_scan_kernel<<<dim3(BATCH, OUTS / (2 * OL)), dim3(OL, G), 0, stream>>>(
        spk, starts, wT, out);
}